// Round 1
// baseline (432.143 us; speedup 1.0000x reference)
//
#include <hip/hip_runtime.h>

// PAFA loss, MI355X. Fixed problem geometry from setup_inputs():
//   N = 262144 rows, D = 256 features, P = 512 patients.
// Math:
//   within  = sum||x||^2 - sum_p cnt_p*||c_p||^2
//   between = P*sum||c_p||^2 - ||sum_p c_p||^2
//   gpal    = S2/P - TT/P^2
//   loss    = 0.1*within/(between+1e-6) + 0.1*gpal

#define DIMS 256
#define NPAT 512
#define SLICES 4
#define SLICE_COLS 64      // DIMS / SLICES
#define RB 64              // row-blocks
#define BLOCK1 1024
#define ACC_PITCH 65       // +1 pad: bank = (pid + col) mod 32, breaks pid alignment

// ws layout (bytes):
//   0    : scalars[3] = {SumSq, S1, S2}
//   64   : T[256] float
//   1088 : counts[512] uint
//   4096 : sums area (partials RB*NPAT*DIMS floats, or single copy NPAT*DIMS)

extern "C" __global__ void __launch_bounds__(BLOCK1)
pafa_pass1(const float* __restrict__ feats, const int* __restrict__ pids,
           int N, float* __restrict__ sums_out, unsigned* __restrict__ counts,
           float* __restrict__ scalars, int use_partials)
{
    __shared__ float acc[NPAT * ACC_PITCH];   // 130 KiB
    __shared__ unsigned cnt[NPAT];            // 2 KiB

    const int b     = blockIdx.x;
    const int slice = b & (SLICES - 1);
    const int rb    = b >> 2;                 // log2(SLICES)
    const int tid   = threadIdx.x;

    for (int i = tid; i < NPAT * ACC_PITCH; i += BLOCK1) acc[i] = 0.0f;
    for (int i = tid; i < NPAT; i += BLOCK1) cnt[i] = 0u;
    __syncthreads();

    const int rows_pb = (N + RB - 1) / RB;
    const int r0 = rb * rows_pb;
    const int r1 = (r0 + rows_pb < N) ? (r0 + rows_pb) : N;
    const int cg    = tid & 15;               // 16 col-groups of float4 per row-slice
    const int rsub  = tid >> 4;               // 64 rows in flight per block iter
    const int cbase = slice * SLICE_COLS + cg * 4;

    float ssq = 0.0f;
    for (int r = r0 + rsub; r < r1; r += BLOCK1 / 16) {
        const int pid = pids[r];
        const float4 v = *reinterpret_cast<const float4*>(feats + (size_t)r * DIMS + cbase);
        ssq += v.x * v.x + v.y * v.y + v.z * v.z + v.w * v.w;
        float* a = acc + pid * ACC_PITCH + cg * 4;
        atomicAdd(a + 0, v.x);
        atomicAdd(a + 1, v.y);
        atomicAdd(a + 2, v.z);
        atomicAdd(a + 3, v.w);
        if (slice == 0 && cg == 0) atomicAdd(&cnt[pid], 1u);
    }
    __syncthreads();

    // commit segmented sums for this (rb, slice)
    if (use_partials) {
        float* dst = sums_out + (size_t)rb * (NPAT * DIMS);
        for (int i = tid; i < NPAT * SLICE_COLS; i += BLOCK1) {
            const int p = i >> 6;             // /SLICE_COLS
            const int c = i & (SLICE_COLS - 1);
            dst[p * DIMS + slice * SLICE_COLS + c] = acc[p * ACC_PITCH + c];
        }
    } else {
        for (int i = tid; i < NPAT * SLICE_COLS; i += BLOCK1) {
            const int p = i >> 6;
            const int c = i & (SLICE_COLS - 1);
            atomicAdd(&sums_out[p * DIMS + slice * SLICE_COLS + c],
                      acc[p * ACC_PITCH + c]);
        }
    }
    if (slice == 0) {
        for (int i = tid; i < NPAT; i += BLOCK1)
            if (cnt[i]) atomicAdd(&counts[i], cnt[i]);
    }

    // sum of squares: wave reduce, one atomic per wave
    for (int off = 32; off; off >>= 1) ssq += __shfl_down(ssq, off, 64);
    if ((tid & 63) == 0) atomicAdd(&scalars[0], ssq);
}

extern "C" __global__ void __launch_bounds__(256)
pafa_pass2(const float* __restrict__ sums, const unsigned* __restrict__ counts,
           int ncopies, float* __restrict__ T, float* __restrict__ scalars)
{
    const int p = blockIdx.x;
    const int d = threadIdx.x;

    float s = 0.0f;
    for (int k = 0; k < ncopies; ++k)
        s += sums[(size_t)k * (NPAT * DIMS) + p * DIMS + d];

    const float cntf = fmaxf((float)counts[p], 1.0f);
    const float c = s / cntf;

    atomicAdd(&T[d], c);

    float csq = c * c;
    for (int off = 32; off; off >>= 1) csq += __shfl_down(csq, off, 64);
    __shared__ float red[4];
    if ((d & 63) == 0) red[d >> 6] = csq;
    __syncthreads();
    if (d == 0) {
        const float s2p = red[0] + red[1] + red[2] + red[3];
        atomicAdd(&scalars[2], s2p);          // S2 += ||c_p||^2
        atomicAdd(&scalars[1], cntf * s2p);   // S1 += cnt_p * ||c_p||^2
    }
}

extern "C" __global__ void __launch_bounds__(256)
pafa_pass3(const float* __restrict__ T, const float* __restrict__ scalars,
           const int* __restrict__ nump, float* __restrict__ out)
{
    const int d = threadIdx.x;
    float t = T[d];
    float tt = t * t;
    for (int off = 32; off; off >>= 1) tt += __shfl_down(tt, off, 64);
    __shared__ float red[4];
    if ((d & 63) == 0) red[d >> 6] = tt;
    __syncthreads();
    if (d == 0) {
        const double TT    = (double)red[0] + red[1] + red[2] + red[3];
        const double SumSq = (double)scalars[0];
        const double S1    = (double)scalars[1];
        const double S2    = (double)scalars[2];
        const double Pd    = (double)(*nump);
        const double within  = SumSq - S1;
        const double between = Pd * S2 - TT;
        const double pcsl = within / (between + 1e-6);
        const double gpal = S2 / Pd - TT / (Pd * Pd);
        out[0] = (float)(0.1 * pcsl + 0.1 * gpal);
    }
}

extern "C" void kernel_launch(void* const* d_in, const int* in_sizes, int n_in,
                              void* d_out, int out_size, void* d_ws, size_t ws_size,
                              hipStream_t stream)
{
    const float* feats = (const float*)d_in[0];
    const int*   pids  = (const int*)d_in[1];
    const int*   nump  = (const int*)d_in[2];
    float*       out   = (float*)d_out;

    const int N = in_sizes[0] / DIMS;

    char* ws = (char*)d_ws;
    float*    scalars = (float*)ws;
    float*    T       = (float*)(ws + 64);
    unsigned* counts  = (unsigned*)(ws + 64 + 1024);
    float*    sums    = (float*)(ws + 4096);

    const size_t partial_bytes = (size_t)RB * NPAT * DIMS * sizeof(float);
    const int use_partials = (ws_size >= 4096 + partial_bytes) ? 1 : 0;

    // zero scalars/T/counts every call (harness does not re-poison between replays)
    hipMemsetAsync(ws, 0, 4096, stream);
    if (!use_partials) {
        // single-copy sums must start at zero (accumulated via atomics)
        hipMemsetAsync(sums, 0, (size_t)NPAT * DIMS * sizeof(float), stream);
    }
    // partials path: every element of the partial buffer is overwritten by stores

    pafa_pass1<<<dim3(SLICES * RB), dim3(BLOCK1), 0, stream>>>(
        feats, pids, N, sums, counts, scalars, use_partials);

    pafa_pass2<<<dim3(NPAT), dim3(DIMS), 0, stream>>>(
        sums, counts, use_partials ? RB : 1, T, scalars);

    pafa_pass3<<<dim3(1), dim3(DIMS), 0, stream>>>(T, scalars, nump, out);
}

// Round 2
// 197.531 us; speedup vs baseline: 2.1877x; 2.1877x over previous
//
#include <hip/hip_runtime.h>

// PAFA loss, MI355X. N=262144 rows, D=256 cols, P=512 patients.
//   within  = sum||x||^2 - sum_p cnt_p*||c_p||^2
//   between = P*sum||c_p||^2 - ||sum_p c_p||^2
//   gpal    = S2/P - TT/P^2
//   loss    = 0.1*within/(between+1e-6) + 0.1*gpal
//
// Strategy: counting-sort row indices by patient (3 cheap passes over 1 MB
// of ids), then one block per patient streams its rows with coalesced
// float4 loads and pure register accumulation — no atomics in the hot loop.

#define DIMS 256
#define NPAT 512

// ws layout (bytes)  [ws >= 32 MB, verified round 1]
//   0       : counts  u32[512]
//   2048    : starts  u32[512]
//   4096    : cursor  u32[512]
//   6144    : scalars f32[4] = {SumSq, S1, S2, -}
//   8192    : centroids f32[512*256]   (512 KB)
//   532480  : idx u32[N]               (1 MB)

extern "C" __global__ void __launch_bounds__(1024)
k_hist(const int* __restrict__ pids, int N, unsigned* __restrict__ counts)
{
    __shared__ unsigned h[NPAT];
    const int t = threadIdx.x;
    if (t < NPAT) h[t] = 0u;
    __syncthreads();
    const int r = blockIdx.x * 1024 + t;
    if (r < N) atomicAdd(&h[pids[r]], 1u);
    __syncthreads();
    if (t < NPAT && h[t]) atomicAdd(&counts[t], h[t]);
}

extern "C" __global__ void __launch_bounds__(NPAT)
k_scan(const unsigned* __restrict__ counts, unsigned* __restrict__ starts,
       unsigned* __restrict__ cursor, float* __restrict__ scalars)
{
    __shared__ unsigned tmp[NPAT];
    const int t = threadIdx.x;
    const unsigned c = counts[t];
    tmp[t] = c;
    __syncthreads();
    for (int off = 1; off < NPAT; off <<= 1) {
        const unsigned v = (t >= off) ? tmp[t - off] : 0u;
        __syncthreads();
        tmp[t] += v;
        __syncthreads();
    }
    const unsigned st = tmp[t] - c;   // exclusive
    starts[t] = st;
    cursor[t] = st;
    if (t < 4) scalars[t] = 0.0f;
}

extern "C" __global__ void __launch_bounds__(1024)
k_scatter(const int* __restrict__ pids, int N,
          unsigned* __restrict__ cursor, unsigned* __restrict__ idx)
{
    const int r = blockIdx.x * 1024 + threadIdx.x;
    if (r < N) {
        const int pid = pids[r];
        const unsigned pos = atomicAdd(&cursor[pid], 1u);
        idx[pos] = (unsigned)r;
    }
}

// One block per patient: 8 waves, each wave reads whole rows (float4/lane),
// accumulates in registers. Combine via LDS at the end.
extern "C" __global__ void __launch_bounds__(512)
k_main(const float* __restrict__ feats, const unsigned* __restrict__ idx,
       const unsigned* __restrict__ counts, const unsigned* __restrict__ starts,
       float* __restrict__ centroids, float* __restrict__ scalars)
{
    __shared__ float part[8][DIMS];
    __shared__ float sred[8];
    __shared__ float cred[4];

    const int p    = blockIdx.x;
    const int lane = threadIdx.x & 63;
    const int w    = threadIdx.x >> 6;        // wave 0..7
    const unsigned start = starts[p];
    const unsigned cnt   = counts[p];

    float ax = 0.f, ay = 0.f, az = 0.f, aw = 0.f;
    float ssq = 0.f;
    const unsigned base = lane * 4;

    for (unsigned j = w; j < cnt; j += 8) {
        const unsigned row = idx[start + j];
        const float4 v = *reinterpret_cast<const float4*>(
            feats + (size_t)row * DIMS + base);
        ax += v.x; ay += v.y; az += v.z; aw += v.w;
        ssq += v.x * v.x + v.y * v.y + v.z * v.z + v.w * v.w;
    }

    part[w][base + 0] = ax;
    part[w][base + 1] = ay;
    part[w][base + 2] = az;
    part[w][base + 3] = aw;
    for (int off = 32; off; off >>= 1) ssq += __shfl_down(ssq, off, 64);
    if (lane == 0) sred[w] = ssq;
    __syncthreads();

    const int d = threadIdx.x;
    if (d < DIMS) {
        float s = 0.f;
        #pragma unroll
        for (int ww = 0; ww < 8; ++ww) s += part[ww][d];
        const float cntf = fmaxf((float)cnt, 1.0f);
        const float c = s / cntf;
        centroids[p * DIMS + d] = c;
        float csq = c * c;
        for (int off = 32; off; off >>= 1) csq += __shfl_down(csq, off, 64);
        if ((d & 63) == 0) cred[d >> 6] = csq;
    }
    __syncthreads();

    if (threadIdx.x == 0) {
        const float s2p = cred[0] + cred[1] + cred[2] + cred[3];
        const float cntf = fmaxf((float)cnt, 1.0f);
        atomicAdd(&scalars[2], s2p);          // S2 += ||c_p||^2
        atomicAdd(&scalars[1], cntf * s2p);   // S1 += cnt_p * ||c_p||^2
        float sq = 0.f;
        #pragma unroll
        for (int ww = 0; ww < 8; ++ww) sq += sred[ww];
        atomicAdd(&scalars[0], sq);           // SumSq
    }
}

extern "C" __global__ void __launch_bounds__(DIMS)
k_final(const float* __restrict__ centroids, const float* __restrict__ scalars,
        const int* __restrict__ nump, float* __restrict__ out)
{
    __shared__ float red[4];
    const int d = threadIdx.x;
    float t = 0.f;
    #pragma unroll 4
    for (int p = 0; p < NPAT; ++p) t += centroids[p * DIMS + d];
    float tt = t * t;
    for (int off = 32; off; off >>= 1) tt += __shfl_down(tt, off, 64);
    if ((d & 63) == 0) red[d >> 6] = tt;
    __syncthreads();
    if (d == 0) {
        const double TT    = (double)red[0] + red[1] + red[2] + red[3];
        const double SumSq = (double)scalars[0];
        const double S1    = (double)scalars[1];
        const double S2    = (double)scalars[2];
        const double Pd    = (double)(*nump);
        const double within  = SumSq - S1;
        const double between = Pd * S2 - TT;
        const double pcsl = within / (between + 1e-6);
        const double gpal = S2 / Pd - TT / (Pd * Pd);
        out[0] = (float)(0.1 * pcsl + 0.1 * gpal);
    }
}

extern "C" void kernel_launch(void* const* d_in, const int* in_sizes, int n_in,
                              void* d_out, int out_size, void* d_ws, size_t ws_size,
                              hipStream_t stream)
{
    const float* feats = (const float*)d_in[0];
    const int*   pids  = (const int*)d_in[1];
    const int*   nump  = (const int*)d_in[2];
    float*       out   = (float*)d_out;

    const int N = in_sizes[0] / DIMS;

    char* ws = (char*)d_ws;
    unsigned* counts    = (unsigned*)(ws);
    unsigned* starts    = (unsigned*)(ws + 2048);
    unsigned* cursor    = (unsigned*)(ws + 4096);
    float*    scalars   = (float*)(ws + 6144);
    float*    centroids = (float*)(ws + 8192);
    unsigned* idx       = (unsigned*)(ws + 8192 + (size_t)NPAT * DIMS * sizeof(float));

    // counts accumulated via atomics -> must start zeroed every call
    hipMemsetAsync(counts, 0, NPAT * sizeof(unsigned), stream);

    const int nblk = (N + 1023) / 1024;
    k_hist   <<<dim3(nblk), dim3(1024), 0, stream>>>(pids, N, counts);
    k_scan   <<<dim3(1),    dim3(NPAT), 0, stream>>>(counts, starts, cursor, scalars);
    k_scatter<<<dim3(nblk), dim3(1024), 0, stream>>>(pids, N, cursor, idx);
    k_main   <<<dim3(NPAT), dim3(512),  0, stream>>>(feats, idx, counts, starts,
                                                     centroids, scalars);
    k_final  <<<dim3(1),    dim3(DIMS), 0, stream>>>(centroids, scalars, nump, out);
}

// Round 3
// 150.310 us; speedup vs baseline: 2.8750x; 1.3142x over previous
//
#include <hip/hip_runtime.h>

// PAFA loss, MI355X. N=262144 rows, D=256 cols, P=512 patients.
//   within  = sum||x||^2 - sum_p cnt_p*||c_p||^2
//   between = P*sum||c_p||^2 - ||sum_p c_p||^2   (T = sum_p c_p, TT = ||T||^2)
//   gpal    = S2/P - TT/P^2
//   loss    = 0.1*within/(between+1e-6) + 0.1*gpal
//
// Counting-sort rows by patient (per-block hists -> scan -> atomic scatter),
// then one block per patient streams its rows with coalesced float4 loads,
// batched 4 rows/iter for MLP. T accumulated via atomics inside k_main so the
// final kernel is O(D) only.

#define DIMS 256
#define NPAT 512
#define HB 64        // hist blocks
#define HT 1024      // hist threads per block

// ws layout (bytes):
//   0      counts  u32[512]
//   2048   starts  u32[512]
//   4096   cursor  u32[512]
//   6144   scalars f32[4] = {SumSq, S1, S2, -}
//   6400   T       f32[256]
//   8192   bh      u32[HB*512]   (128 KB)
//   139264 idx     u32[N]        (1 MB)

extern "C" __global__ void __launch_bounds__(HT)
k_hist(const int* __restrict__ pids, int N, unsigned* __restrict__ bh)
{
    __shared__ unsigned h[NPAT];
    const int t = threadIdx.x;
    if (t < NPAT) h[t] = 0u;
    __syncthreads();

    const int rows_pb = ((N + HB * 4 - 1) / (HB * 4)) * 4;   // multiple of 4
    const int r = blockIdx.x * rows_pb + t * 4;
    if (r + 3 < N) {
        const int4 p4 = *reinterpret_cast<const int4*>(pids + r);
        atomicAdd(&h[p4.x], 1u);
        atomicAdd(&h[p4.y], 1u);
        atomicAdd(&h[p4.z], 1u);
        atomicAdd(&h[p4.w], 1u);
    } else {
        for (int k = 0; k < 4; ++k)
            if (r + k < N) atomicAdd(&h[pids[r + k]], 1u);
    }
    __syncthreads();
    if (t < NPAT) bh[blockIdx.x * NPAT + t] = h[t];
}

extern "C" __global__ void __launch_bounds__(NPAT)
k_scan(const unsigned* __restrict__ bh, unsigned* __restrict__ counts,
       unsigned* __restrict__ starts, unsigned* __restrict__ cursor,
       float* __restrict__ scalars, float* __restrict__ T)
{
    __shared__ unsigned tmp[NPAT];
    const int t = threadIdx.x;
    unsigned c = 0u;
    #pragma unroll 8
    for (int b = 0; b < HB; ++b) c += bh[b * NPAT + t];
    counts[t] = c;
    tmp[t] = c;
    __syncthreads();
    for (int off = 1; off < NPAT; off <<= 1) {
        const unsigned v = (t >= off) ? tmp[t - off] : 0u;
        __syncthreads();
        tmp[t] += v;
        __syncthreads();
    }
    const unsigned st = tmp[t] - c;   // exclusive
    starts[t] = st;
    cursor[t] = st;
    if (t < 4)    scalars[t] = 0.0f;
    if (t < DIMS) T[t]       = 0.0f;
}

extern "C" __global__ void __launch_bounds__(1024)
k_scatter(const int* __restrict__ pids, int N,
          unsigned* __restrict__ cursor, unsigned* __restrict__ idx)
{
    const int i = (blockIdx.x * 1024 + threadIdx.x) * 4;
    if (i + 3 < N) {
        const int4 p4 = *reinterpret_cast<const int4*>(pids + i);
        idx[atomicAdd(&cursor[p4.x], 1u)] = (unsigned)(i + 0);
        idx[atomicAdd(&cursor[p4.y], 1u)] = (unsigned)(i + 1);
        idx[atomicAdd(&cursor[p4.z], 1u)] = (unsigned)(i + 2);
        idx[atomicAdd(&cursor[p4.w], 1u)] = (unsigned)(i + 3);
    } else {
        for (int k = 0; k < 4; ++k)
            if (i + k < N) idx[atomicAdd(&cursor[pids[i + k]], 1u)] = (unsigned)(i + k);
    }
}

// One block per patient: 8 waves, each wave reads whole rows (float4/lane),
// batched 4 rows per iteration for memory-level parallelism.
extern "C" __global__ void __launch_bounds__(512)
k_main(const float* __restrict__ feats, const unsigned* __restrict__ idx,
       const unsigned* __restrict__ counts, const unsigned* __restrict__ starts,
       float* __restrict__ T, float* __restrict__ scalars)
{
    __shared__ float part[8][DIMS];
    __shared__ float sred[8];
    __shared__ float cred[4];

    const int p    = blockIdx.x;
    const int lane = threadIdx.x & 63;
    const int w    = threadIdx.x >> 6;        // wave 0..7
    const unsigned start = starts[p];
    const unsigned cnt   = counts[p];
    const unsigned base  = lane * 4;

    float ax = 0.f, ay = 0.f, az = 0.f, aw = 0.f;
    float ssq = 0.f;

    unsigned j = (unsigned)w;
    for (; j + 24 < cnt; j += 32) {
        const unsigned r0 = idx[start + j];
        const unsigned r1 = idx[start + j + 8];
        const unsigned r2 = idx[start + j + 16];
        const unsigned r3 = idx[start + j + 24];
        const float4 v0 = *reinterpret_cast<const float4*>(feats + (size_t)r0 * DIMS + base);
        const float4 v1 = *reinterpret_cast<const float4*>(feats + (size_t)r1 * DIMS + base);
        const float4 v2 = *reinterpret_cast<const float4*>(feats + (size_t)r2 * DIMS + base);
        const float4 v3 = *reinterpret_cast<const float4*>(feats + (size_t)r3 * DIMS + base);
        ax += v0.x + v1.x + v2.x + v3.x;
        ay += v0.y + v1.y + v2.y + v3.y;
        az += v0.z + v1.z + v2.z + v3.z;
        aw += v0.w + v1.w + v2.w + v3.w;
        ssq += v0.x*v0.x + v0.y*v0.y + v0.z*v0.z + v0.w*v0.w;
        ssq += v1.x*v1.x + v1.y*v1.y + v1.z*v1.z + v1.w*v1.w;
        ssq += v2.x*v2.x + v2.y*v2.y + v2.z*v2.z + v2.w*v2.w;
        ssq += v3.x*v3.x + v3.y*v3.y + v3.z*v3.z + v3.w*v3.w;
    }
    for (; j < cnt; j += 8) {
        const unsigned row = idx[start + j];
        const float4 v = *reinterpret_cast<const float4*>(feats + (size_t)row * DIMS + base);
        ax += v.x; ay += v.y; az += v.z; aw += v.w;
        ssq += v.x*v.x + v.y*v.y + v.z*v.z + v.w*v.w;
    }

    part[w][base + 0] = ax;
    part[w][base + 1] = ay;
    part[w][base + 2] = az;
    part[w][base + 3] = aw;
    for (int off = 32; off; off >>= 1) ssq += __shfl_down(ssq, off, 64);
    if (lane == 0) sred[w] = ssq;
    __syncthreads();

    const int d = threadIdx.x;
    if (d < DIMS) {
        float s = 0.f;
        #pragma unroll
        for (int ww = 0; ww < 8; ++ww) s += part[ww][d];
        const float cntf = fmaxf((float)cnt, 1.0f);
        const float c = s / cntf;
        atomicAdd(&T[d], c);
        float csq = c * c;
        for (int off = 32; off; off >>= 1) csq += __shfl_down(csq, off, 64);
        if ((d & 63) == 0) cred[d >> 6] = csq;
    }
    __syncthreads();

    if (threadIdx.x == 0) {
        const float s2p = cred[0] + cred[1] + cred[2] + cred[3];
        const float cntf = fmaxf((float)cnt, 1.0f);
        atomicAdd(&scalars[2], s2p);          // S2 += ||c_p||^2
        atomicAdd(&scalars[1], cntf * s2p);   // S1 += cnt_p * ||c_p||^2
        float sq = 0.f;
        #pragma unroll
        for (int ww = 0; ww < 8; ++ww) sq += sred[ww];
        atomicAdd(&scalars[0], sq);           // SumSq
    }
}

extern "C" __global__ void __launch_bounds__(DIMS)
k_final(const float* __restrict__ T, const float* __restrict__ scalars,
        const int* __restrict__ nump, float* __restrict__ out)
{
    __shared__ float red[4];
    const int d = threadIdx.x;
    const float t = T[d];
    float tt = t * t;
    for (int off = 32; off; off >>= 1) tt += __shfl_down(tt, off, 64);
    if ((d & 63) == 0) red[d >> 6] = tt;
    __syncthreads();
    if (d == 0) {
        const double TT    = (double)red[0] + red[1] + red[2] + red[3];
        const double SumSq = (double)scalars[0];
        const double S1    = (double)scalars[1];
        const double S2    = (double)scalars[2];
        const double Pd    = (double)(*nump);
        const double within  = SumSq - S1;
        const double between = Pd * S2 - TT;
        const double pcsl = within / (between + 1e-6);
        const double gpal = S2 / Pd - TT / (Pd * Pd);
        out[0] = (float)(0.1 * pcsl + 0.1 * gpal);
    }
}

extern "C" void kernel_launch(void* const* d_in, const int* in_sizes, int n_in,
                              void* d_out, int out_size, void* d_ws, size_t ws_size,
                              hipStream_t stream)
{
    const float* feats = (const float*)d_in[0];
    const int*   pids  = (const int*)d_in[1];
    const int*   nump  = (const int*)d_in[2];
    float*       out   = (float*)d_out;

    const int N = in_sizes[0] / DIMS;

    char* ws = (char*)d_ws;
    unsigned* counts  = (unsigned*)(ws);
    unsigned* starts  = (unsigned*)(ws + 2048);
    unsigned* cursor  = (unsigned*)(ws + 4096);
    float*    scalars = (float*)(ws + 6144);
    float*    T       = (float*)(ws + 6400);
    unsigned* bh      = (unsigned*)(ws + 8192);
    unsigned* idx     = (unsigned*)(ws + 8192 + (size_t)HB * NPAT * sizeof(unsigned));

    const int scat_blocks = (N + 4095) / 4096;   // 4 rows per thread, 1024 threads

    k_hist   <<<dim3(HB),          dim3(HT),   0, stream>>>(pids, N, bh);
    k_scan   <<<dim3(1),           dim3(NPAT), 0, stream>>>(bh, counts, starts, cursor,
                                                            scalars, T);
    k_scatter<<<dim3(scat_blocks), dim3(1024), 0, stream>>>(pids, N, cursor, idx);
    k_main   <<<dim3(NPAT),        dim3(512),  0, stream>>>(feats, idx, counts, starts,
                                                            T, scalars);
    k_final  <<<dim3(1),           dim3(DIMS), 0, stream>>>(T, scalars, nump, out);
}

// Round 4
// 76.883 us; speedup vs baseline: 5.6208x; 1.9550x over previous
//
#include <hip/hip_runtime.h>

// PAFA loss, MI355X. N=262144 rows, D=256 cols, P=512 patients.
//   within  = sum||x||^2 - sum_p cnt_p*||c_p||^2
//   between = P*sum||c_p||^2 - ||sum_p c_p||^2   (T = sum_p c_p, TT = ||T||^2)
//   gpal    = S2/P - TT/P^2
//   loss    = 0.1*within/(between+1e-6) + 0.1*gpal
//
// Counting-sort rows by patient, then one block per patient streams its rows
// with coalesced float4 loads (8 rows in flight per wave). Scatter uses
// per-block range reservation (1 global atomic per block x patient) + padded
// cursors (64B/patient) to kill same-line atomic serialization.

#define DIMS 256
#define NPAT 512
#define HB 64        // hist/scatter blocks
#define HT 1024      // threads per hist/scatter block
#define CPAD 16      // cursor stride in u32 (64 B per patient)

// ws layout (bytes):
//   0      counts  u32[512]
//   2048   starts  u32[512]
//   4096   scalars f32[4] = {SumSq, S1, S2, -}
//   4352   T       f32[256]
//   8192   cursor  u32[512*16]  (32 KB, 64B per patient)
//   40960  bh      u32[512*64]  transposed [pat][block] (128 KB)
//   173056 idx     u32[N]       (1 MB)

extern "C" __global__ void __launch_bounds__(HT)
k_hist(const int* __restrict__ pids, int N, unsigned* __restrict__ bh)
{
    __shared__ unsigned h[NPAT];
    const int t = threadIdx.x;
    if (t < NPAT) h[t] = 0u;
    __syncthreads();

    const int r = (blockIdx.x * HT + t) * 4;   // N = HB*HT*4 exactly for 262144
    if (r + 3 < N) {
        const int4 p4 = *reinterpret_cast<const int4*>(pids + r);
        atomicAdd(&h[p4.x], 1u);
        atomicAdd(&h[p4.y], 1u);
        atomicAdd(&h[p4.z], 1u);
        atomicAdd(&h[p4.w], 1u);
    } else {
        for (int k = 0; k < 4; ++k)
            if (r + k < N) atomicAdd(&h[pids[r + k]], 1u);
    }
    __syncthreads();
    if (t < NPAT) bh[t * HB + blockIdx.x] = h[t];   // transposed
}

extern "C" __global__ void __launch_bounds__(NPAT)
k_scan(const unsigned* __restrict__ bh, unsigned* __restrict__ counts,
       unsigned* __restrict__ starts, unsigned* __restrict__ cursor,
       float* __restrict__ scalars, float* __restrict__ T)
{
    __shared__ unsigned tmp[NPAT];
    const int t = threadIdx.x;
    unsigned c = 0u;
    const uint4* row = reinterpret_cast<const uint4*>(bh + t * HB);
    #pragma unroll
    for (int k = 0; k < HB / 4; ++k) {
        const uint4 v = row[k];
        c += v.x + v.y + v.z + v.w;
    }
    counts[t] = c;
    tmp[t] = c;
    __syncthreads();
    for (int off = 1; off < NPAT; off <<= 1) {
        const unsigned v = (t >= off) ? tmp[t - off] : 0u;
        __syncthreads();
        tmp[t] += v;
        __syncthreads();
    }
    const unsigned st = tmp[t] - c;   // exclusive
    starts[t] = st;
    cursor[t * CPAD] = st;
    if (t < 4)    scalars[t] = 0.0f;
    if (t < DIMS) T[t]       = 0.0f;
}

// Per-block reservation scatter: LDS hist -> 1 global atomic per (block,pat)
// reserving a contiguous range -> LDS-cursor placement.
extern "C" __global__ void __launch_bounds__(HT)
k_scatter(const int* __restrict__ pids, int N,
          unsigned* __restrict__ cursor, unsigned* __restrict__ idx)
{
    __shared__ unsigned h[NPAT];
    __shared__ unsigned basec[NPAT];
    __shared__ int      spid[HT * 4];   // 16 KB

    const int t = threadIdx.x;
    if (t < NPAT) h[t] = 0u;
    __syncthreads();

    const int r = (blockIdx.x * HT + t) * 4;
    int4 p4 = make_int4(-1, -1, -1, -1);
    if (r + 3 < N) {
        p4 = *reinterpret_cast<const int4*>(pids + r);
        atomicAdd(&h[p4.x], 1u);
        atomicAdd(&h[p4.y], 1u);
        atomicAdd(&h[p4.z], 1u);
        atomicAdd(&h[p4.w], 1u);
    } else {
        if (r + 0 < N) { p4.x = pids[r + 0]; atomicAdd(&h[p4.x], 1u); }
        if (r + 1 < N) { p4.y = pids[r + 1]; atomicAdd(&h[p4.y], 1u); }
        if (r + 2 < N) { p4.z = pids[r + 2]; atomicAdd(&h[p4.z], 1u); }
        if (r + 3 < N) { p4.w = pids[r + 3]; atomicAdd(&h[p4.w], 1u); }
    }
    spid[t * 4 + 0] = p4.x;
    spid[t * 4 + 1] = p4.y;
    spid[t * 4 + 2] = p4.z;
    spid[t * 4 + 3] = p4.w;
    __syncthreads();

    if (t < NPAT) {
        const unsigned hc = h[t];
        basec[t] = hc ? atomicAdd(&cursor[t * CPAD], hc) : 0u;
    }
    __syncthreads();

    #pragma unroll
    for (int k = 0; k < 4; ++k) {
        const int pid = spid[t * 4 + k];
        if (pid >= 0) {
            const unsigned pos = atomicAdd(&basec[pid], 1u);
            idx[pos] = (unsigned)(r + k);
        }
    }
}

// One block per patient: 8 waves, each wave reads whole rows (float4/lane),
// 8 rows in flight per wave for memory-level parallelism.
extern "C" __global__ void __launch_bounds__(512)
k_main(const float* __restrict__ feats, const unsigned* __restrict__ idx,
       const unsigned* __restrict__ counts, const unsigned* __restrict__ starts,
       float* __restrict__ T, float* __restrict__ scalars)
{
    __shared__ float part[8][DIMS];
    __shared__ float sred[8];
    __shared__ float cred[4];

    const int p    = blockIdx.x;
    const int lane = threadIdx.x & 63;
    const int w    = threadIdx.x >> 6;        // wave 0..7
    const unsigned start = starts[p];
    const unsigned cnt   = counts[p];
    const unsigned base  = lane * 4;

    float ax = 0.f, ay = 0.f, az = 0.f, aw = 0.f;
    float ssq = 0.f;

    unsigned j = (unsigned)w;
    for (; j + 56 < cnt; j += 64) {
        unsigned rr[8];
        #pragma unroll
        for (int k = 0; k < 8; ++k) rr[k] = idx[start + j + 8 * k];
        float4 v[8];
        #pragma unroll
        for (int k = 0; k < 8; ++k)
            v[k] = *reinterpret_cast<const float4*>(feats + (size_t)rr[k] * DIMS + base);
        #pragma unroll
        for (int k = 0; k < 8; ++k) {
            ax += v[k].x; ay += v[k].y; az += v[k].z; aw += v[k].w;
            ssq += v[k].x*v[k].x + v[k].y*v[k].y + v[k].z*v[k].z + v[k].w*v[k].w;
        }
    }
    for (; j < cnt; j += 8) {
        const unsigned row = idx[start + j];
        const float4 v = *reinterpret_cast<const float4*>(feats + (size_t)row * DIMS + base);
        ax += v.x; ay += v.y; az += v.z; aw += v.w;
        ssq += v.x*v.x + v.y*v.y + v.z*v.z + v.w*v.w;
    }

    part[w][base + 0] = ax;
    part[w][base + 1] = ay;
    part[w][base + 2] = az;
    part[w][base + 3] = aw;
    for (int off = 32; off; off >>= 1) ssq += __shfl_down(ssq, off, 64);
    if (lane == 0) sred[w] = ssq;
    __syncthreads();

    const int d = threadIdx.x;
    if (d < DIMS) {
        float s = 0.f;
        #pragma unroll
        for (int ww = 0; ww < 8; ++ww) s += part[ww][d];
        const float cntf = fmaxf((float)cnt, 1.0f);
        const float c = s / cntf;
        atomicAdd(&T[d], c);
        float csq = c * c;
        for (int off = 32; off; off >>= 1) csq += __shfl_down(csq, off, 64);
        if ((d & 63) == 0) cred[d >> 6] = csq;
    }
    __syncthreads();

    if (threadIdx.x == 0) {
        const float s2p = cred[0] + cred[1] + cred[2] + cred[3];
        const float cntf = fmaxf((float)cnt, 1.0f);
        atomicAdd(&scalars[2], s2p);          // S2 += ||c_p||^2
        atomicAdd(&scalars[1], cntf * s2p);   // S1 += cnt_p * ||c_p||^2
        float sq = 0.f;
        #pragma unroll
        for (int ww = 0; ww < 8; ++ww) sq += sred[ww];
        atomicAdd(&scalars[0], sq);           // SumSq
    }
}

extern "C" __global__ void __launch_bounds__(DIMS)
k_final(const float* __restrict__ T, const float* __restrict__ scalars,
        const int* __restrict__ nump, float* __restrict__ out)
{
    __shared__ float red[4];
    const int d = threadIdx.x;
    const float t = T[d];
    float tt = t * t;
    for (int off = 32; off; off >>= 1) tt += __shfl_down(tt, off, 64);
    if ((d & 63) == 0) red[d >> 6] = tt;
    __syncthreads();
    if (d == 0) {
        const double TT    = (double)red[0] + red[1] + red[2] + red[3];
        const double SumSq = (double)scalars[0];
        const double S1    = (double)scalars[1];
        const double S2    = (double)scalars[2];
        const double Pd    = (double)(*nump);
        const double within  = SumSq - S1;
        const double between = Pd * S2 - TT;
        const double pcsl = within / (between + 1e-6);
        const double gpal = S2 / Pd - TT / (Pd * Pd);
        out[0] = (float)(0.1 * pcsl + 0.1 * gpal);
    }
}

extern "C" void kernel_launch(void* const* d_in, const int* in_sizes, int n_in,
                              void* d_out, int out_size, void* d_ws, size_t ws_size,
                              hipStream_t stream)
{
    const float* feats = (const float*)d_in[0];
    const int*   pids  = (const int*)d_in[1];
    const int*   nump  = (const int*)d_in[2];
    float*       out   = (float*)d_out;

    const int N = in_sizes[0] / DIMS;

    char* ws = (char*)d_ws;
    unsigned* counts  = (unsigned*)(ws);
    unsigned* starts  = (unsigned*)(ws + 2048);
    float*    scalars = (float*)(ws + 4096);
    float*    T       = (float*)(ws + 4352);
    unsigned* cursor  = (unsigned*)(ws + 8192);
    unsigned* bh      = (unsigned*)(ws + 40960);
    unsigned* idx     = (unsigned*)(ws + 173056);

    k_hist   <<<dim3(HB),   dim3(HT),   0, stream>>>(pids, N, bh);
    k_scan   <<<dim3(1),    dim3(NPAT), 0, stream>>>(bh, counts, starts, cursor,
                                                     scalars, T);
    k_scatter<<<dim3(HB),   dim3(HT),   0, stream>>>(pids, N, cursor, idx);
    k_main   <<<dim3(NPAT), dim3(512),  0, stream>>>(feats, idx, counts, starts,
                                                     T, scalars);
    k_final  <<<dim3(1),    dim3(DIMS), 0, stream>>>(T, scalars, nump, out);
}